// Round 16
// baseline (691.279 us; speedup 1.0000x reference)
//
#include <hip/hip_runtime.h>
#include <hip/hip_bf16.h>

constexpr int Nn = 20000;
constexpr int Ee = 320000;
constexpr int Dd = 256;
constexpr int Bb = 16;
constexpr float EPSc = 1e-5f;

using v8s = __attribute__((ext_vector_type(8))) short;
using v4f = __attribute__((ext_vector_type(4))) float;
using v2f = __attribute__((ext_vector_type(2))) float;

__device__ __forceinline__ float b2f(ushort u) { return __uint_as_float(((unsigned)u) << 16); }
__device__ __forceinline__ ushort f2b(float f) {
  __hip_bfloat16 h = __float2bfloat16(f);
  return *reinterpret_cast<ushort*>(&h);
}

#ifndef __has_builtin
#define __has_builtin(x) 0
#endif
#if __has_builtin(__builtin_amdgcn_cvt_pk_f32_fp8) && __has_builtin(__builtin_amdgcn_cvt_pk_fp8_f32)
#define FP8CVT 1
#else
#define FP8CVT 0
#endif

__device__ __forceinline__ unsigned f2fp8(float v) {
#if FP8CVT
  return (unsigned)__builtin_amdgcn_cvt_pk_fp8_f32(v, 0.f, 0, false) & 0xFFu;
#else
  unsigned u = __float_as_uint(v);
  unsigned s = (u >> 24) & 0x80u;
  unsigned a = u & 0x7FFFFFFFu;
  if (a >= 0x43F00000u) return s | 0x7Eu;
  unsigned r = a + 0x0007FFFFu + ((a >> 20) & 1u);
  int e = (int)(r >> 23) - 120;
  if (e <= 0) return s;
  return s | ((unsigned)e << 3) | ((r >> 20) & 7u);
#endif
}

__device__ __forceinline__ void fp8x8_dec(unsigned lo, unsigned hi, float* f) {
#if FP8CVT
  v2f p0 = __builtin_amdgcn_cvt_pk_f32_fp8((int)lo, false);
  v2f p1 = __builtin_amdgcn_cvt_pk_f32_fp8((int)lo, true);
  v2f p2 = __builtin_amdgcn_cvt_pk_f32_fp8((int)hi, false);
  v2f p3 = __builtin_amdgcn_cvt_pk_f32_fp8((int)hi, true);
  f[0] = p0[0]; f[1] = p0[1]; f[2] = p1[0]; f[3] = p1[1];
  f[4] = p2[0]; f[5] = p2[1]; f[6] = p3[0]; f[7] = p3[1];
#else
#pragma unroll
  for (int j = 0; j < 8; ++j) {
    unsigned b = (j < 4) ? ((lo >> (8 * j)) & 0xFFu) : ((hi >> (8 * (j - 4))) & 0xFFu);
    unsigned s = (b & 0x80u) << 24;
    unsigned e = (b >> 3) & 15u, m = b & 7u;
    float x;
    if (e) x = __uint_as_float(s | ((e + 120u) << 23) | (m << 20));
    else { x = (float)(int)m * 0x1p-9f; if (s) x = -x; }
    f[j] = x;
  }
#endif
}

// ------------------------------------------------------------------ graph prep
__global__ void hist_edges_k(const int* __restrict__ src, const int* __restrict__ dst,
                             int* __restrict__ cin, int* __restrict__ cout) {
  int e = blockIdx.x * 256 + threadIdx.x;
  if (e < Ee) { atomicAdd(&cin[dst[e]], 1); atomicAdd(&cout[src[e]], 1); }
}

__global__ void cnt_batch_k(const int* __restrict__ batch, float* __restrict__ cntf) {
  int b = threadIdx.x;
  if (b < Bb) {
    int lo = 0, hi = Nn;
    while (lo < hi) { int mid = (lo + hi) >> 1; if (batch[mid] < b) lo = mid + 1; else hi = mid; }
    int lb = lo;
    lo = 0; hi = Nn;
    while (lo < hi) { int mid = (lo + hi) >> 1; if (batch[mid] <= b) lo = mid + 1; else hi = mid; }
    cntf[b] = (float)(lo - lb);
  }
}

__global__ __launch_bounds__(1024) void scan_k(const int* __restrict__ cin,
                                               const int* __restrict__ cout,
                                               int* __restrict__ off_in, int* __restrict__ off_out,
                                               int* __restrict__ cur_in, int* __restrict__ cur_out) {
  __shared__ int part[1024];
  const int tid = threadIdx.x;
  for (int which = 0; which < 2; ++which) {
    const int* cnt = which ? cout : cin;
    int* off = which ? off_out : off_in;
    int* curp = which ? cur_out : cur_in;
    int vals[20];
    int base = tid * 20;
    int local = 0;
#pragma unroll
    for (int i = 0; i < 20; ++i) {
      int idx = base + i;
      int v = (idx < Nn) ? cnt[idx] : 0;
      vals[i] = v; local += v;
    }
    part[tid] = local;
    __syncthreads();
    for (int ofs = 1; ofs < 1024; ofs <<= 1) {
      int t = (tid >= ofs) ? part[tid - ofs] : 0;
      __syncthreads();
      part[tid] += t;
      __syncthreads();
    }
    int run = part[tid] - local;
#pragma unroll
    for (int i = 0; i < 20; ++i) {
      int idx = base + i;
      if (idx < Nn) { off[idx] = run; curp[idx] = run; run += vals[i]; }
    }
    if (tid == 0) off[Nn] = Ee;
    __syncthreads();
  }
}

__global__ void scatter_k(const int* __restrict__ src, const int* __restrict__ dst,
                          int* __restrict__ cur_in, int* __restrict__ cur_out,
                          int* __restrict__ in_src, int* __restrict__ in_eid,
                          int* __restrict__ out_dst, int* __restrict__ out_eid,
                          int* __restrict__ out_srcn) {
  int e = blockIdx.x * 256 + threadIdx.x;
  if (e < Ee) {
    int d = dst[e], s = src[e];
    int p = atomicAdd(&cur_in[d], 1);  in_src[p] = s;  in_eid[p] = e;
    int q = atomicAdd(&cur_out[s], 1); out_dst[q] = d; out_eid[q] = e; out_srcn[q] = s;
  }
}

__global__ void prep_bsum_k(const float* __restrict__ bs, const float* __restrict__ bin,
                            const float* __restrict__ bout, float* __restrict__ bsum) {
  int t = threadIdx.x;
  for (int l = 0; l < 3; ++l) bsum[l * 256 + t] = bs[l * 256 + t] + bin[l * 256 + t] + bout[l * 256 + t];
}

__global__ void copyxb_k(const float* __restrict__ x, ushort* __restrict__ h) {
  const int n4 = Nn * Dd / 4;
  int i = blockIdx.x * 256 + threadIdx.x;
  if (i < n4) {
    float4 v = ((const float4*)x)[i];
    ushort4 o; o.x = f2b(v.x); o.y = f2b(v.y); o.z = f2b(v.z); o.w = f2b(v.w);
    ((ushort4*)h)[i] = o;
  }
}

__global__ void c_f2b_k(const float* __restrict__ s, ushort* __restrict__ d, int n) {
  int i = blockIdx.x * 256 + threadIdx.x;
  if (i < n) d[i] = f2b(s[i]);
}

__global__ void prep_mlp_k(const float* __restrict__ mw1, const float* __restrict__ mb1,
                           const float* __restrict__ mw2,
                           ushort* __restrict__ Wcombb, ushort* __restrict__ W2b,
                           float* __restrict__ bcomb) {
  int i = blockIdx.x * 256 + threadIdx.x;
  if (i < 65536) {
    int r = i >> 8, c = i & 255;
    float v = (r < 128) ? mw1[r * 512 + c] : mw1[(r - 128) * 512 + 256 + c];
    Wcombb[i] = f2b(v);
  }
  if (i < 8192) W2b[i] = f2b(mw2[i]);
  if (i < 256) bcomb[i] = (i < 128) ? mb1[i] : 0.f;
}

__global__ void permmask_k(const float* __restrict__ mask,
                           const int* __restrict__ in_eid, float* __restrict__ minA) {
  int i = blockIdx.x * 256 + threadIdx.x;
  if (i < Ee) minA[i] = mask[in_eid[i]];
}

// ------------------------------------------------------------------ GEMM768 tiled, double-buffered LDS
// EMIT8 0: bf16 out ; 1: fp8 e4m3fn out
template <int EMIT8>
__global__ __launch_bounds__(256) void gemm768t_k(
    const ushort* __restrict__ A, const ushort* __restrict__ W0,
    const ushort* __restrict__ W1, const ushort* __restrict__ W2,
    ushort* __restrict__ Y, unsigned char* __restrict__ Y8, int M) {
  __shared__ ushort lds[20480];  // 2 x (As 5120 + Bs 5120)
  const int tid = threadIdx.x;
  const int wid = tid >> 6, lane = tid & 63;
  const int wr = wid & 1, wc = wid >> 1;
  const int m0 = blockIdx.x * 128;
  const int by = blockIdx.y;
  const int seg = by >> 1;
  const ushort* Wp = (seg == 0) ? W0 : ((seg == 1) ? W1 : W2);
  const int nb0 = (by & 1) * 128;
  const int lrow = lane & 15;
  const int klo = (lane >> 4) * 8;
  const int r0 = tid >> 2, c80 = (tid & 3) * 8;
  const int r1 = (tid + 256) >> 2, c81 = ((tid + 256) & 3) * 8;
  int ar0 = m0 + r0; if (ar0 >= M) ar0 = M - 1;
  int ar1 = m0 + r1; if (ar1 >= M) ar1 = M - 1;
  const ushort* Ap0 = A + (size_t)ar0 * 256 + c80;
  const ushort* Ap1 = A + (size_t)ar1 * 256 + c81;
  const ushort* Wp0 = Wp + (size_t)(nb0 + r0) * 256 + c80;
  const ushort* Wp1 = Wp + (size_t)(nb0 + r1) * 256 + c81;

  v8s sa0, sa1, sb0, sb1;
  sa0 = *(const v8s*)(Ap0);  sa1 = *(const v8s*)(Ap1);
  sb0 = *(const v8s*)(Wp0);  sb1 = *(const v8s*)(Wp1);
  {
    ushort* As = lds; ushort* Bs = lds + 5120;
    *(v8s*)&As[r0 * 40 + c80] = sa0;  *(v8s*)&As[r1 * 40 + c81] = sa1;
    *(v8s*)&Bs[r0 * 40 + c80] = sb0;  *(v8s*)&Bs[r1 * 40 + c81] = sb1;
  }
  __syncthreads();
  v4f acc[4][4] = {};
#pragma unroll
  for (int it = 0; it < 8; ++it) {
    const int cur = it & 1;
    ushort* Asc = lds + cur * 10240;
    ushort* Bsc = Asc + 5120;
    if (it < 7) {  // issue next-tile global loads (overlap with MFMA below)
      const int kc = (it + 1) * 32;
      sa0 = *(const v8s*)(Ap0 + kc);  sa1 = *(const v8s*)(Ap1 + kc);
      sb0 = *(const v8s*)(Wp0 + kc);  sb1 = *(const v8s*)(Wp1 + kc);
    }
    v8s a[4], b[4];
#pragma unroll
    for (int f = 0; f < 4; ++f) {
      a[f] = *(const v8s*)&Asc[(wr * 64 + f * 16 + lrow) * 40 + klo];
      b[f] = *(const v8s*)&Bsc[(wc * 64 + f * 16 + lrow) * 40 + klo];
    }
#pragma unroll
    for (int fi = 0; fi < 4; ++fi)
#pragma unroll
      for (int fj = 0; fj < 4; ++fj)
        acc[fi][fj] = __builtin_amdgcn_mfma_f32_16x16x32_bf16(a[fi], b[fj], acc[fi][fj], 0, 0, 0);
    if (it < 7) {
      ushort* Asn = lds + (cur ^ 1) * 10240;
      ushort* Bsn = Asn + 5120;
      *(v8s*)&Asn[r0 * 40 + c80] = sa0;  *(v8s*)&Asn[r1 * 40 + c81] = sa1;
      *(v8s*)&Bsn[r0 * 40 + c80] = sb0;  *(v8s*)&Bsn[r1 * 40 + c81] = sb1;
      __syncthreads();
    }
  }
  __syncthreads();  // drain last reads before epilogue overlay
  const int colq = by * 128 + wc * 64;
  if (EMIT8) {
    unsigned char* ep = (unsigned char*)lds + wid * 3072;  // [32][96]
#pragma unroll
    for (int hf = 0; hf < 2; ++hf) {
#pragma unroll
      for (int fi = 0; fi < 2; ++fi) {
        const int fI = hf * 2 + fi;
        const int rl0 = fi * 16 + ((lane >> 4) << 2);
#pragma unroll
        for (int fj = 0; fj < 4; ++fj)
#pragma unroll
          for (int r = 0; r < 4; ++r)
            ep[(rl0 + r) * 96 + fj * 16 + lrow] = (unsigned char)f2fp8(acc[fI][fj][r]);
      }
#pragma unroll
      for (int i = 0; i < 2; ++i) {
        const int rl = (lane >> 2) + i * 16;
        const int cb = (lane & 3) * 16;
        uint4 val = *(const uint4*)&ep[rl * 96 + cb];
        const int grow = m0 + wr * 64 + hf * 32 + rl;
        if (grow < M)
          *(uint4*)(Y8 + (size_t)grow * 768 + colq + cb) = val;
      }
    }
  } else {
    ushort* ep = lds + wid * 2304;  // [32][72]
#pragma unroll
    for (int hf = 0; hf < 2; ++hf) {
#pragma unroll
      for (int fi = 0; fi < 2; ++fi) {
        const int fI = hf * 2 + fi;
        const int rl0 = fi * 16 + ((lane >> 4) << 2);
#pragma unroll
        for (int fj = 0; fj < 4; ++fj)
#pragma unroll
          for (int r = 0; r < 4; ++r)
            ep[(rl0 + r) * 72 + fj * 16 + lrow] = f2b(acc[fI][fj][r]);
      }
#pragma unroll
      for (int i = 0; i < 4; ++i) {
        const int rl = (lane >> 2) + (i & 1) * 16;
        const int oct = (lane & 3) + (i >> 1) * 4;
        v8s val = *(const v8s*)&ep[rl * 72 + oct * 8];
        const int grow = m0 + wr * 64 + hf * 32 + rl;
        if (grow < M)
          *(v8s*)(Y + (size_t)grow * 768 + colq + oct * 8) = val;
      }
    }
  }
}

// ------------------------------------------------------------------ agg + epilogue (bf16 tables)
template <int MODE, int WR>
__global__ __launch_bounds__(256) void aggepi_k(
    const ushort* __restrict__ Y, ushort* __restrict__ hout, ushort* __restrict__ raw,
    const int* __restrict__ off_in, const int* __restrict__ in_src,
    const int* __restrict__ off_out, const int* __restrict__ out_dst,
    const float* __restrict__ minA, const float* __restrict__ moutA,
    const float* __restrict__ bsum, const float* __restrict__ gma,
    const float* __restrict__ bta, const float* __restrict__ rmn, const float* __restrict__ rvr,
    int Mtot) {
  const int g = threadIdx.x >> 5;
  const int lane = threadIdx.x & 31;
  const int node = blockIdx.x * 8 + g;
  if (node >= Mtot) return;
  const int v = node;
  const int co = lane * 8;
  float acc[8] = {};
#pragma unroll
  for (int dir = 0; dir < 2; ++dir) {
    const int* offs = dir ? off_out : off_in;
    const int* nbr  = dir ? out_dst : in_src;
    const float* ma = dir ? moutA : minA;
    const ushort* Yg = Y + (dir ? 512 : 256) + co;
    const int s = offs[v], e = offs[v + 1];
    int i = s;
    for (; i + 4 <= e; i += 4) {
      int u[4]; float m[4];
#pragma unroll
      for (int t = 0; t < 4; ++t) {
        u[t] = nbr[i + t];
        m[t] = (MODE == 0) ? 1.f : ma[i + t];
      }
      v8s r[4];
#pragma unroll
      for (int t = 0; t < 4; ++t) r[t] = *(const v8s*)(Yg + (size_t)u[t] * 768);
#pragma unroll
      for (int t = 0; t < 4; ++t)
#pragma unroll
        for (int j = 0; j < 8; ++j) acc[j] += m[t] * b2f((ushort)r[t][j]);
    }
    for (; i < e; ++i) {
      int u = nbr[i];
      float m = (MODE == 0) ? 1.f : ma[i];
      v8s r = *(const v8s*)(Yg + (size_t)u * 768);
#pragma unroll
      for (int j = 0; j < 8; ++j) acc[j] += m * b2f((ushort)r[j]);
    }
  }
  if (WR) {
    v8s rw;
#pragma unroll
    for (int j = 0; j < 8; ++j) rw[j] = (short)f2b(acc[j]);
    *(v8s*)(raw + (size_t)v * 256 + co) = rw;
  }
  v8s ys = *(const v8s*)(Y + (size_t)v * 768 + co);
  v8s o;
#pragma unroll
  for (int j = 0; j < 8; ++j) {
    const int col = co + j;
    float val = acc[j] + b2f((ushort)ys[j]) + bsum[col];
    val = fmaxf(val, 0.f);
    val = (val - rmn[col]) * rsqrtf(rvr[col] + EPSc) * gma[col] + bta[col];
    o[j] = (short)f2b(val);
  }
  *(v8s*)(hout + (size_t)node * 256 + co) = o;
}

// ------------------------------------------------------------------ agg + epilogue (fp8 tables, dual-half batched)
__global__ __launch_bounds__(256) void aggepi8_k(
    const unsigned char* __restrict__ Y8, ushort* __restrict__ hout,
    const int* __restrict__ off_in, const int* __restrict__ in_src,
    const int* __restrict__ off_out, const int* __restrict__ out_dst,
    const float* __restrict__ minA, const float* __restrict__ moutA,
    const float* __restrict__ bsum, const float* __restrict__ gma,
    const float* __restrict__ bta, const float* __restrict__ rmn, const float* __restrict__ rvr) {
  const int g = threadIdx.x >> 5;
  const int lane = threadIdx.x & 31;
  const int node = blockIdx.x * 8 + g;
  if (node >= 2 * Nn) return;
  const int half = (node >= Nn) ? 1 : 0;
  const int v = node - half * Nn;
  const int co = lane * 8;
  float acc[8] = {};
#pragma unroll
  for (int dir = 0; dir < 2; ++dir) {
    const int* offs = dir ? off_out : off_in;
    const int* nbr  = dir ? out_dst : in_src;
    const float* ma = dir ? moutA : minA;
    const unsigned char* Yg = Y8 + (size_t)half * Nn * 768 + (dir ? 512 : 256) + co;
    const int s = offs[v], e = offs[v + 1];
    int i = s;
    for (; i + 4 <= e; i += 4) {
      int u[4]; float m[4];
#pragma unroll
      for (int t = 0; t < 4; ++t) {
        u[t] = nbr[i + t];
        float mv = ma[i + t];
        m[t] = half ? (1.f - mv) : mv;
      }
      uint2 r[4];
#pragma unroll
      for (int t = 0; t < 4; ++t) r[t] = *(const uint2*)(Yg + (size_t)u[t] * 768);
#pragma unroll
      for (int t = 0; t < 4; ++t) {
        float f[8];
        fp8x8_dec(r[t].x, r[t].y, f);
#pragma unroll
        for (int j = 0; j < 8; ++j) acc[j] += m[t] * f[j];
      }
    }
    for (; i < e; ++i) {
      int u = nbr[i];
      float mv = ma[i];
      float m = half ? (1.f - mv) : mv;
      uint2 r = *(const uint2*)(Yg + (size_t)u * 768);
      float f[8];
      fp8x8_dec(r.x, r.y, f);
#pragma unroll
      for (int j = 0; j < 8; ++j) acc[j] += m * f[j];
    }
  }
  uint2 rs = *(const uint2*)(Y8 + (size_t)(half * Nn + v) * 768 + co);
  float fs[8];
  fp8x8_dec(rs.x, rs.y, fs);
  v8s o;
#pragma unroll
  for (int j = 0; j < 8; ++j) {
    const int col = co + j;
    float val = acc[j] + fs[j] + bsum[col];
    val = fmaxf(val, 0.f);
    val = (val - rmn[col]) * rsqrtf(rvr[col] + EPSc) * gma[col] + bta[col];
    o[j] = (short)f2b(val);
  }
  *(v8s*)(hout + (size_t)node * 256 + co) = o;
}

// batched L0 comp half
__global__ void compl0_k(const ushort* __restrict__ Yx, const ushort* __restrict__ Aones,
                         const ushort* __restrict__ Asub, ushort* __restrict__ hout,
                         const float* __restrict__ bsum, const float* __restrict__ gma,
                         const float* __restrict__ bta, const float* __restrict__ rmn,
                         const float* __restrict__ rvr) {
  int i = blockIdx.x * 256 + threadIdx.x;
  if (i >= Nn * 32) return;
  const int v = i >> 5;
  const int co = (i & 31) * 8;
  v8s ys = *(const v8s*)(Yx + (size_t)v * 768 + co);
  v8s ao = *(const v8s*)(Aones + (size_t)v * 256 + co);
  v8s as = *(const v8s*)(Asub + (size_t)v * 256 + co);
  v8s o;
#pragma unroll
  for (int j = 0; j < 8; ++j) {
    const int col = co + j;
    float val = b2f((ushort)ys[j]) + b2f((ushort)ao[j]) - b2f((ushort)as[j]) + bsum[col];
    val = fmaxf(val, 0.f);
    val = (val - rmn[col]) * rsqrtf(rvr[col] + EPSc) * gma[col] + bta[col];
    o[j] = (short)f2b(val);
  }
  *(v8s*)(hout + (size_t)(Nn + v) * 256 + co) = o;
}

// ------------------------------------------------------------------ proj GEMM (mask MLP layer 1)
template <int EPI>
__global__ __launch_bounds__(256) void mfma_gemm2_k(
    const ushort* __restrict__ A, const ushort* __restrict__ W,
    ushort* __restrict__ Cout, int M, const float* __restrict__ bias) {
  __shared__ ushort eplds[4][32][72];
  const int tid = threadIdx.x;
  const int wid = tid >> 6, lane = tid & 63;
  const int wr = wid & 1, wc = wid >> 1;
  const int m0 = blockIdx.x * 64 + wr * 32;
  const int n0 = blockIdx.y * 128 + wc * 64;
  const int lrow = lane & 15;
  const int klo = (lane >> 4) * 8;
  int rowA[2];
#pragma unroll
  for (int fi = 0; fi < 2; ++fi) {
    int r = m0 + fi * 16 + lrow;
    rowA[fi] = (r < M) ? r : (M - 1);
  }
  v4f acc[2][4] = {};
#pragma unroll
  for (int c = 0; c < 8; ++c) {
    v8s a[2], b[4];
#pragma unroll
    for (int fi = 0; fi < 2; ++fi)
      a[fi] = *(const v8s*)(A + (size_t)rowA[fi] * 256 + c * 32 + klo);
#pragma unroll
    for (int fj = 0; fj < 4; ++fj)
      b[fj] = *(const v8s*)(W + (size_t)(n0 + fj * 16 + lrow) * 256 + c * 32 + klo);
#pragma unroll
    for (int fi = 0; fi < 2; ++fi)
#pragma unroll
      for (int fj = 0; fj < 4; ++fj)
        acc[fi][fj] = __builtin_amdgcn_mfma_f32_16x16x32_bf16(a[fi], b[fj], acc[fi][fj], 0, 0, 0);
  }
#pragma unroll
  for (int fj = 0; fj < 4; ++fj) {
    const int col = n0 + fj * 16 + lrow;
    const float bsv = bias ? bias[col] : 0.f;
#pragma unroll
    for (int fi = 0; fi < 2; ++fi) {
      const int rl0 = fi * 16 + ((lane >> 4) << 2);
#pragma unroll
      for (int r = 0; r < 4; ++r)
        eplds[wid][rl0 + r][fj * 16 + lrow] = f2b(acc[fi][fj][r] + bsv);
    }
  }
#pragma unroll
  for (int i = 0; i < 4; ++i) {
    const int rl = (lane >> 2) + (i & 1) * 16;
    const int oct = (lane & 3) + (i >> 1) * 4;
    v8s val = *(const v8s*)&eplds[wid][rl][oct * 8];
    const int grow = m0 + rl;
    if (grow < M)
      *(v8s*)(Cout + (size_t)grow * 256 + n0 + oct * 8) = val;
  }
}

// ------------------------------------------------------------------ edge MLP over out-CSR order
__global__ __launch_bounds__(256) void edge_mlp4_k(const ushort* __restrict__ P,
                                                   const int* __restrict__ out_srcn,
                                                   const int* __restrict__ out_dst,
                                                   const int* __restrict__ out_eid,
                                                   const ushort* __restrict__ W2b,
                                                   const float* __restrict__ b2, const float* __restrict__ w3,
                                                   const float* __restrict__ b3,
                                                   float* __restrict__ maskOut, float* __restrict__ moutA) {
  const int tid = threadIdx.x;
  const int w = tid >> 6, lane = tid & 63;
  const int e0 = blockIdx.x * 64 + w * 16;
  const int le = lane & 15;
  const int kq = lane >> 4;
  const int klo = kq * 8;
  const int pA = e0 + le;
  const int s_ = out_srcn[pA], d_ = out_dst[pA];
  const ushort* ps = P + (size_t)s_ * 256;
  const ushort* pd = P + (size_t)d_ * 256 + 128;
  v8s as[4], ad[4];
#pragma unroll
  for (int c = 0; c < 4; ++c) {
    as[c] = *(const v8s*)(ps + c * 32 + klo);
    ad[c] = *(const v8s*)(pd + c * 32 + klo);
  }
  v4f acc[4] = {};
  __builtin_amdgcn_s_setprio(1);
#pragma unroll
  for (int c = 0; c < 4; ++c) {
    v8s h;
#pragma unroll
    for (int j = 0; j < 8; ++j) {
      float v = fmaxf(b2f((ushort)as[c][j]) + b2f((ushort)ad[c][j]), 0.f);
      h[j] = (short)f2b(v);
    }
#pragma unroll
    for (int fj = 0; fj < 4; ++fj) {
      v8s b = *(const v8s*)(W2b + (size_t)(fj * 16 + le) * 128 + c * 32 + klo);
      acc[fj] = __builtin_amdgcn_mfma_f32_16x16x32_bf16(h, b, acc[fj], 0, 0, 0);
    }
  }
  __builtin_amdgcn_s_setprio(0);
  float b2v[4], w3v[4];
#pragma unroll
  for (int fj = 0; fj < 4; ++fj) { b2v[fj] = b2[fj * 16 + le]; w3v[fj] = w3[fj * 16 + le]; }
  const float b3v = b3[0];
#pragma unroll
  for (int r = 0; r < 4; ++r) {
    float val = 0.f;
#pragma unroll
    for (int fj = 0; fj < 4; ++fj)
      val += fmaxf(acc[fj][r] + b2v[fj], 0.f) * w3v[fj];
    val += __shfl_xor(val, 1);
    val += __shfl_xor(val, 2);
    val += __shfl_xor(val, 4);
    val += __shfl_xor(val, 8);
    if (le == 0) {
      int pos = e0 + kq * 4 + r;
      float sig = 1.0f / (1.0f + expf(-(val + b3v)));
      moutA[pos] = sig;
      maskOut[out_eid[pos]] = sig;
    }
  }
}

// ------------------------------------------------------------------ pooling / tails
__global__ __launch_bounds__(256) void gemb_sum_k(const ushort* __restrict__ h, const int* __restrict__ batch,
                                                  float* __restrict__ gsum, int batched) {
  const int halfBlocks = Nn / 16;
  int blk = blockIdx.x;
  int half = 0, bi = blk;
  if (batched) { half = (blk >= halfBlocks) ? 1 : 0; bi = blk - half * halfBlocks; }
  const int v0 = bi * 16;
  const int tid = threadIdx.x;
  const size_t base = (size_t)half * Nn;
  float* out = gsum + (size_t)half * (Bb * Dd);
  float acc = 0.0f;
  int curb = batch[v0];
  for (int i = 0; i < 16; ++i) {
    int v = v0 + i;
    int b = batch[v];
    if (b != curb) { atomicAdd(&out[curb * Dd + tid], acc); acc = 0.0f; curb = b; }
    acc += b2f(h[(base + v) * Dd + tid]);
  }
  atomicAdd(&out[curb * Dd + tid], acc);
}

__global__ void gemb_scale_k(float* __restrict__ g, const float* __restrict__ cntf) {
  int blk = blockIdx.x;
  int b = blk & 15;
  g[blk * Dd + threadIdx.x] /= fmaxf(cntf[b], 1.0f);
}

__global__ void anchor_k(const float* __restrict__ g, const float* __restrict__ anchors,
                         float* __restrict__ s_out) {
  __shared__ float red4[4];
  const int b = blockIdx.x, tid = threadIdx.x;
  float gv = g[b * Dd + tid];
  float total = 0.0f;
  for (int k = 0; k < 6; ++k) {
    float d = gv - anchors[k * Dd + tid];
    float v = d * d;
    for (int o = 32; o > 0; o >>= 1) v += __shfl_xor(v, o);
    if ((tid & 63) == 0) red4[tid >> 6] = v;
    __syncthreads();
    if (tid == 0) total += sqrtf(red4[0] + red4[1] + red4[2] + red4[3]);
    __syncthreads();
  }
  if (tid == 0) s_out[b] = total;
}

__global__ void logits_k(const float* __restrict__ gsub, const float* __restrict__ gcomp,
                         const float* __restrict__ Wc, const float* __restrict__ bc,
                         float* __restrict__ outL) {
  __shared__ float red4[4];
  const int blk = blockIdx.x;
  const int set = blk >> 4, b = blk & 15;
  const float* g = set ? gcomp : gsub;
  const int tid = threadIdx.x;
  float gv = g[b * Dd + tid];
  for (int c = 0; c < 2; ++c) {
    float v = gv * Wc[c * Dd + tid];
    for (int o = 32; o > 0; o >>= 1) v += __shfl_xor(v, o);
    if ((tid & 63) == 0) red4[tid >> 6] = v;
    __syncthreads();
    if (tid == 0) outL[set * 32 + b * 2 + c] = red4[0] + red4[1] + red4[2] + red4[3] + bc[c];
    __syncthreads();
  }
}

__global__ void final_k(const float* __restrict__ L, const int* __restrict__ labels,
                        const float* __restrict__ s_orig, const float* __restrict__ s_sub,
                        float* __restrict__ out) {
  if (threadIdx.x == 0) {
    float Lp = 0, Lu = 0, La = 0;
    const float u = 0.5f;
    for (int b = 0; b < 16; ++b) {
      float l0 = L[b * 2], l1 = L[b * 2 + 1];
      float m = fmaxf(l0, l1);
      float lse = m + logf(expf(l0 - m) + expf(l1 - m));
      int lab = labels[b];
      Lp += -((lab ? l1 : l0) - lse);
      float c0 = L[32 + b * 2], c1 = L[32 + b * 2 + 1];
      float mm = fmaxf(c0, c1);
      float e0 = expf(c0 - mm), e1 = expf(c1 - mm), Z = e0 + e1;
      Lu += u * (logf(u) - logf(e0 / Z + 1e-8f)) + u * (logf(u) - logf(e1 / Z + 1e-8f));
      float dd = s_sub[b] - s_orig[b];
      La += dd * dd;
    }
    Lp /= 16.0f; Lu /= 16.0f; La /= 16.0f;
    out[0] = 0.5f * Lp + 0.3f * Lu + 0.2f * La;
    out[1] = Lp; out[2] = Lu; out[3] = La;
  }
}

// ------------------------------------------------------------------ host
extern "C" void kernel_launch(void* const* d_in, const int* in_sizes, int n_in,
                              void* d_out, int out_size, void* d_ws, size_t ws_size,
                              hipStream_t stream) {
  (void)in_sizes; (void)n_in; (void)out_size; (void)ws_size;
  const float* x    = (const float*)d_in[0];
  const int* ei     = (const int*)d_in[1];
  const int* batch  = (const int*)d_in[2];
  const int* labels = (const int*)d_in[3];
  const float* mw1 = (const float*)d_in[4];
  const float* mb1 = (const float*)d_in[5];
  const float* mw2 = (const float*)d_in[6];
  const float* mb2 = (const float*)d_in[7];
  const float* mw3 = (const float*)d_in[8];
  const float* mb3 = (const float*)d_in[9];
  const float* Ws   = (const float*)d_in[10];
  const float* bs   = (const float*)d_in[11];
  const float* Win  = (const float*)d_in[12];
  const float* bin_ = (const float*)d_in[13];
  const float* Wout = (const float*)d_in[14];
  const float* bout = (const float*)d_in[15];
  const float* gma  = (const float*)d_in[16];
  const float* bta  = (const float*)d_in[17];
  const float* rmn  = (const float*)d_in[18];
  const float* rvr  = (const float*)d_in[19];
  const float* anchors = (const float*)d_in[20];
  const float* Wc   = (const float*)d_in[21];
  const float* bc   = (const float*)d_in[22];
  const int* srcp = ei;
  const int* dstp = ei + Ee;

  const size_t NH = (size_t)Nn * Dd;
  const size_t NY = (size_t)Nn * 768;
  ushort* xb   = (ushort*)d_ws;
  ushort* hA   = xb + NH;
  ushort* hB   = hA + 2 * NH;
  ushort* Yx   = hB + 2 * NH;
  ushort* Ybuf = Yx + NY;
  ushort* Pb   = Ybuf;
  unsigned char* Y8 = (unsigned char*)Ybuf;
  ushort* Aones = Ybuf + 2 * NY;
  ushort* Asub  = Aones + NH;
  ushort* Wsb   = Asub + NH;
  ushort* Winb  = Wsb + 3 * 65536;
  ushort* Woutb = Winb + 3 * 65536;
  ushort* Wcombb = Woutb + 3 * 65536;
  ushort* W2b    = Wcombb + 65536;
  float* bcomb = (float*)(W2b + 8192);
  float* minA  = bcomb + 256;
  float* moutA = minA + Ee;
  int* off_in   = (int*)(moutA + Ee);
  int* off_out  = off_in + (Nn + 1);
  int* cur_in   = off_out + (Nn + 1);
  int* cur_out  = cur_in + Nn;
  int* in_src   = cur_out + Nn;
  int* in_eid   = in_src + Ee;
  int* out_dst  = in_eid + Ee;
  int* out_eid  = out_dst + Ee;
  int* out_srcn = out_eid + Ee;
  int* counts_in  = out_srcn + Ee;
  int* counts_out = counts_in + Nn;
  float* cntf      = (float*)(counts_out + Nn);
  float* gemb_orig = cntf + Bb;
  float* gemb_sub  = gemb_orig + Bb * Dd;
  float* gemb_comp = gemb_sub + Bb * Dd;
  float* bsum    = gemb_comp + Bb * Dd;
  float* s_orig  = bsum + 3 * Dd;
  float* s_sub   = s_orig + Bb;
  float* logitsb = s_sub + Bb;

  float* outF = (float*)d_out;
  float* maskp = outF + 4;

  const size_t zero_bytes = (char*)bsum - (char*)counts_in;
  hipMemsetAsync(counts_in, 0, zero_bytes, stream);

  hist_edges_k<<<(Ee + 255) / 256, 256, 0, stream>>>(srcp, dstp, counts_in, counts_out);
  cnt_batch_k<<<1, 64, 0, stream>>>(batch, cntf);
  scan_k<<<1, 1024, 0, stream>>>(counts_in, counts_out, off_in, off_out, cur_in, cur_out);
  scatter_k<<<(Ee + 255) / 256, 256, 0, stream>>>(srcp, dstp, cur_in, cur_out, in_src, in_eid,
                                                  out_dst, out_eid, out_srcn);
  prep_bsum_k<<<1, 256, 0, stream>>>(bs, bin_, bout, bsum);

  c_f2b_k<<<(3 * 65536 + 255) / 256, 256, 0, stream>>>(Ws, Wsb, 3 * 65536);
  c_f2b_k<<<(3 * 65536 + 255) / 256, 256, 0, stream>>>(Win, Winb, 3 * 65536);
  c_f2b_k<<<(3 * 65536 + 255) / 256, 256, 0, stream>>>(Wout, Woutb, 3 * 65536);
  prep_mlp_k<<<256, 256, 0, stream>>>(mw1, mb1, mw2, Wcombb, W2b, bcomb);

  auto run_gemm768 = [&](const ushort* h, ushort* Yout, int M, int l) {
    dim3 gg((M + 127) / 128, 6);
    gemm768t_k<0><<<gg, 256, 0, stream>>>(h, Wsb + (size_t)l * 65536, Winb + (size_t)l * 65536,
                                          Woutb + (size_t)l * 65536, Yout, nullptr, M);
  };
  auto run_gemm768_8 = [&](const ushort* h, int M, int l) {
    dim3 gg((M + 127) / 128, 6);
    gemm768t_k<1><<<gg, 256, 0, stream>>>(h, Wsb + (size_t)l * 65536, Winb + (size_t)l * 65536,
                                          Woutb + (size_t)l * 65536, nullptr, Y8, M);
  };
  auto bn = [&](int l) { return bsum + l * 256; };
  const int aggN = (Nn + 7) / 8;
  const int agg2N = (2 * Nn + 7) / 8;

  // ---- encoder #1 (ones mask), bf16 throughout
  copyxb_k<<<(Nn * Dd / 4 + 255) / 256, 256, 0, stream>>>(x, xb);
  run_gemm768(xb, Yx, Nn, 0);
  aggepi_k<0, 1><<<aggN, 256, 0, stream>>>(
      Yx, hB, Aones, off_in, in_src, off_out, out_dst, nullptr, nullptr,
      bn(0), gma, bta, rmn, rvr, Nn);
  run_gemm768(hB, Ybuf, Nn, 1);
  aggepi_k<0, 0><<<aggN, 256, 0, stream>>>(
      Ybuf, hA, nullptr, off_in, in_src, off_out, out_dst, nullptr, nullptr,
      bn(1), gma + 256, bta + 256, rmn + 256, rvr + 256, Nn);
  run_gemm768(hA, Ybuf, Nn, 2);
  aggepi_k<0, 0><<<aggN, 256, 0, stream>>>(
      Ybuf, hB, nullptr, off_in, in_src, off_out, out_dst, nullptr, nullptr,
      bn(2), gma + 512, bta + 512, rmn + 512, rvr + 512, Nn);
  // node_emb = hB

  gemb_sum_k<<<Nn / 16, 256, 0, stream>>>(hB, batch, gemb_orig, 0);
  gemb_scale_k<<<Bb, 256, 0, stream>>>(gemb_orig, cntf);
  anchor_k<<<Bb, 256, 0, stream>>>(gemb_orig, anchors, s_orig);

  // ---- packed projection P (Pb aliases Ybuf)
  {
    dim3 gp((Nn + 63) / 64, 2);
    mfma_gemm2_k<3><<<gp, 256, 0, stream>>>(hB, Wcombb, Pb, Nn, bcomb);
  }
  edge_mlp4_k<<<Ee / 64, 256, 0, stream>>>(Pb, out_srcn, out_dst, out_eid,
                                           W2b, mb2, mw3, mb3, maskp, moutA);
  permmask_k<<<(Ee + 255) / 256, 256, 0, stream>>>(maskp, in_eid, minA);

  // ---- batched encoders #2/#3 (mask & 1-mask)
  aggepi_k<1, 1><<<aggN, 256, 0, stream>>>(
      Yx, hA, Asub, off_in, in_src, off_out, out_dst, minA, moutA,
      bn(0), gma, bta, rmn, rvr, Nn);
  compl0_k<<<(Nn * 32 + 255) / 256, 256, 0, stream>>>(Yx, Aones, Asub, hA,
                                                      bn(0), gma, bta, rmn, rvr);
  // L1 (fp8 Y table + dual-half fp8 agg)
  run_gemm768_8(hA, 2 * Nn, 1);
  aggepi8_k<<<agg2N, 256, 0, stream>>>(
      Y8, hB, off_in, in_src, off_out, out_dst, minA, moutA,
      bn(1), gma + 256, bta + 256, rmn + 256, rvr + 256);
  // L2
  run_gemm768_8(hB, 2 * Nn, 2);
  aggepi8_k<<<agg2N, 256, 0, stream>>>(
      Y8, hA, off_in, in_src, off_out, out_dst, minA, moutA,
      bn(2), gma + 512, bta + 512, rmn + 512, rvr + 512);
  // hA = [h_sub; h_comp]

  gemb_sum_k<<<2 * (Nn / 16), 256, 0, stream>>>(hA, batch, gemb_sub, 1);
  gemb_scale_k<<<2 * Bb, 256, 0, stream>>>(gemb_sub, cntf);
  anchor_k<<<Bb, 256, 0, stream>>>(gemb_sub, anchors, s_sub);
  logits_k<<<2 * Bb, 256, 0, stream>>>(gemb_sub, gemb_comp, Wc, bc, logitsb);
  final_k<<<1, 64, 0, stream>>>(logitsb, labels, s_orig, s_sub, outF);
}

// Round 17
// 686.163 us; speedup vs baseline: 1.0075x; 1.0075x over previous
//
#include <hip/hip_runtime.h>
#include <hip/hip_bf16.h>

constexpr int Nn = 20000;
constexpr int Ee = 320000;
constexpr int Dd = 256;
constexpr int Bb = 16;
constexpr float EPSc = 1e-5f;

using v8s = __attribute__((ext_vector_type(8))) short;
using v4f = __attribute__((ext_vector_type(4))) float;
using v2f = __attribute__((ext_vector_type(2))) float;

__device__ __forceinline__ float b2f(ushort u) { return __uint_as_float(((unsigned)u) << 16); }
__device__ __forceinline__ ushort f2b(float f) {
  __hip_bfloat16 h = __float2bfloat16(f);
  return *reinterpret_cast<ushort*>(&h);
}

#ifndef __has_builtin
#define __has_builtin(x) 0
#endif
#if __has_builtin(__builtin_amdgcn_cvt_pk_f32_fp8) && __has_builtin(__builtin_amdgcn_cvt_pk_fp8_f32)
#define FP8CVT 1
#else
#define FP8CVT 0
#endif

__device__ __forceinline__ unsigned f2fp8(float v) {
#if FP8CVT
  return (unsigned)__builtin_amdgcn_cvt_pk_fp8_f32(v, 0.f, 0, false) & 0xFFu;
#else
  unsigned u = __float_as_uint(v);
  unsigned s = (u >> 24) & 0x80u;
  unsigned a = u & 0x7FFFFFFFu;
  if (a >= 0x43F00000u) return s | 0x7Eu;
  unsigned r = a + 0x0007FFFFu + ((a >> 20) & 1u);
  int e = (int)(r >> 23) - 120;
  if (e <= 0) return s;
  return s | ((unsigned)e << 3) | ((r >> 20) & 7u);
#endif
}

__device__ __forceinline__ void fp8x8_dec(unsigned lo, unsigned hi, float* f) {
#if FP8CVT
  v2f p0 = __builtin_amdgcn_cvt_pk_f32_fp8((int)lo, false);
  v2f p1 = __builtin_amdgcn_cvt_pk_f32_fp8((int)lo, true);
  v2f p2 = __builtin_amdgcn_cvt_pk_f32_fp8((int)hi, false);
  v2f p3 = __builtin_amdgcn_cvt_pk_f32_fp8((int)hi, true);
  f[0] = p0[0]; f[1] = p0[1]; f[2] = p1[0]; f[3] = p1[1];
  f[4] = p2[0]; f[5] = p2[1]; f[6] = p3[0]; f[7] = p3[1];
#else
#pragma unroll
  for (int j = 0; j < 8; ++j) {
    unsigned b = (j < 4) ? ((lo >> (8 * j)) & 0xFFu) : ((hi >> (8 * (j - 4))) & 0xFFu);
    unsigned s = (b & 0x80u) << 24;
    unsigned e = (b >> 3) & 15u, m = b & 7u;
    float x;
    if (e) x = __uint_as_float(s | ((e + 120u) << 23) | (m << 20));
    else { x = (float)(int)m * 0x1p-9f; if (s) x = -x; }
    f[j] = x;
  }
#endif
}

// ------------------------------------------------------------------ graph prep
__global__ void hist_edges_k(const int* __restrict__ src, const int* __restrict__ dst,
                             int* __restrict__ cin, int* __restrict__ cout) {
  int e = blockIdx.x * 256 + threadIdx.x;
  if (e < Ee) { atomicAdd(&cin[dst[e]], 1); atomicAdd(&cout[src[e]], 1); }
}

__global__ void cnt_batch_k(const int* __restrict__ batch, float* __restrict__ cntf) {
  int b = threadIdx.x;
  if (b < Bb) {
    int lo = 0, hi = Nn;
    while (lo < hi) { int mid = (lo + hi) >> 1; if (batch[mid] < b) lo = mid + 1; else hi = mid; }
    int lb = lo;
    lo = 0; hi = Nn;
    while (lo < hi) { int mid = (lo + hi) >> 1; if (batch[mid] <= b) lo = mid + 1; else hi = mid; }
    cntf[b] = (float)(lo - lb);
  }
}

__global__ __launch_bounds__(1024) void scan_k(const int* __restrict__ cin,
                                               const int* __restrict__ cout,
                                               int* __restrict__ off_in, int* __restrict__ off_out,
                                               int* __restrict__ cur_in, int* __restrict__ cur_out) {
  __shared__ int part[1024];
  const int tid = threadIdx.x;
  for (int which = 0; which < 2; ++which) {
    const int* cnt = which ? cout : cin;
    int* off = which ? off_out : off_in;
    int* curp = which ? cur_out : cur_in;
    int vals[20];
    int base = tid * 20;
    int local = 0;
#pragma unroll
    for (int i = 0; i < 20; ++i) {
      int idx = base + i;
      int v = (idx < Nn) ? cnt[idx] : 0;
      vals[i] = v; local += v;
    }
    part[tid] = local;
    __syncthreads();
    for (int ofs = 1; ofs < 1024; ofs <<= 1) {
      int t = (tid >= ofs) ? part[tid - ofs] : 0;
      __syncthreads();
      part[tid] += t;
      __syncthreads();
    }
    int run = part[tid] - local;
#pragma unroll
    for (int i = 0; i < 20; ++i) {
      int idx = base + i;
      if (idx < Nn) { off[idx] = run; curp[idx] = run; run += vals[i]; }
    }
    if (tid == 0) off[Nn] = Ee;
    __syncthreads();
  }
}

__global__ void scatter_k(const int* __restrict__ src, const int* __restrict__ dst,
                          int* __restrict__ cur_in, int* __restrict__ cur_out,
                          int* __restrict__ in_src, int* __restrict__ in_eid,
                          int* __restrict__ out_dst, int* __restrict__ out_eid,
                          int* __restrict__ out_srcn) {
  int e = blockIdx.x * 256 + threadIdx.x;
  if (e < Ee) {
    int d = dst[e], s = src[e];
    int p = atomicAdd(&cur_in[d], 1);  in_src[p] = s;  in_eid[p] = e;
    int q = atomicAdd(&cur_out[s], 1); out_dst[q] = d; out_eid[q] = e; out_srcn[q] = s;
  }
}

__global__ void prep_bsum_k(const float* __restrict__ bs, const float* __restrict__ bin,
                            const float* __restrict__ bout, float* __restrict__ bsum) {
  int t = threadIdx.x;
  for (int l = 0; l < 3; ++l) bsum[l * 256 + t] = bs[l * 256 + t] + bin[l * 256 + t] + bout[l * 256 + t];
}

__global__ void copyxb_k(const float* __restrict__ x, ushort* __restrict__ h) {
  const int n4 = Nn * Dd / 4;
  int i = blockIdx.x * 256 + threadIdx.x;
  if (i < n4) {
    float4 v = ((const float4*)x)[i];
    ushort4 o; o.x = f2b(v.x); o.y = f2b(v.y); o.z = f2b(v.z); o.w = f2b(v.w);
    ((ushort4*)h)[i] = o;
  }
}

__global__ void c_f2b_k(const float* __restrict__ s, ushort* __restrict__ d, int n) {
  int i = blockIdx.x * 256 + threadIdx.x;
  if (i < n) d[i] = f2b(s[i]);
}

__global__ void prep_mlp_k(const float* __restrict__ mw1, const float* __restrict__ mb1,
                           const float* __restrict__ mw2,
                           ushort* __restrict__ Wcombb, ushort* __restrict__ W2b,
                           float* __restrict__ bcomb) {
  int i = blockIdx.x * 256 + threadIdx.x;
  if (i < 65536) {
    int r = i >> 8, c = i & 255;
    float v = (r < 128) ? mw1[r * 512 + c] : mw1[(r - 128) * 512 + 256 + c];
    Wcombb[i] = f2b(v);
  }
  if (i < 8192) W2b[i] = f2b(mw2[i]);
  if (i < 256) bcomb[i] = (i < 128) ? mb1[i] : 0.f;
}

__global__ void permmask_k(const float* __restrict__ mask,
                           const int* __restrict__ in_eid, float* __restrict__ minA) {
  int i = blockIdx.x * 256 + threadIdx.x;
  if (i < Ee) minA[i] = mask[in_eid[i]];
}

// ------------------------------------------------------------------ GEMM768 tiled: LDS-staged 128x128 (single buffer)
// EMIT8 0: bf16 out ; 1: fp8 e4m3fn out
template <int EMIT8>
__global__ __launch_bounds__(256) void gemm768t_k(
    const ushort* __restrict__ A, const ushort* __restrict__ W0,
    const ushort* __restrict__ W1, const ushort* __restrict__ W2,
    ushort* __restrict__ Y, unsigned char* __restrict__ Y8, int M) {
  __shared__ ushort lds[10240];
  ushort* As = lds;
  ushort* Bs = lds + 5120;
  const int tid = threadIdx.x;
  const int wid = tid >> 6, lane = tid & 63;
  const int wr = wid & 1, wc = wid >> 1;
  const int m0 = blockIdx.x * 128;
  const int by = blockIdx.y;
  const int seg = by >> 1;
  const ushort* Wp = (seg == 0) ? W0 : ((seg == 1) ? W1 : W2);
  const int nb0 = (by & 1) * 128;
  const int lrow = lane & 15;
  const int klo = (lane >> 4) * 8;
  const int r0 = tid >> 2, c80 = (tid & 3) * 8;
  const int r1 = (tid + 256) >> 2, c81 = ((tid + 256) & 3) * 8;
  int ar0 = m0 + r0; if (ar0 >= M) ar0 = M - 1;
  int ar1 = m0 + r1; if (ar1 >= M) ar1 = M - 1;
  v4f acc[4][4] = {};
  for (int kc = 0; kc < 256; kc += 32) {
    __syncthreads();
    *(v8s*)&As[r0 * 40 + c80] = *(const v8s*)(A + (size_t)ar0 * 256 + kc + c80);
    *(v8s*)&As[r1 * 40 + c81] = *(const v8s*)(A + (size_t)ar1 * 256 + kc + c81);
    *(v8s*)&Bs[r0 * 40 + c80] = *(const v8s*)(Wp + (size_t)(nb0 + r0) * 256 + kc + c80);
    *(v8s*)&Bs[r1 * 40 + c81] = *(const v8s*)(Wp + (size_t)(nb0 + r1) * 256 + kc + c81);
    __syncthreads();
    v8s a[4], b[4];
#pragma unroll
    for (int f = 0; f < 4; ++f) {
      a[f] = *(const v8s*)&As[(wr * 64 + f * 16 + lrow) * 40 + klo];
      b[f] = *(const v8s*)&Bs[(wc * 64 + f * 16 + lrow) * 40 + klo];
    }
#pragma unroll
    for (int fi = 0; fi < 4; ++fi)
#pragma unroll
      for (int fj = 0; fj < 4; ++fj)
        acc[fi][fj] = __builtin_amdgcn_mfma_f32_16x16x32_bf16(a[fi], b[fj], acc[fi][fj], 0, 0, 0);
  }
  __syncthreads();
  const int colq = by * 128 + wc * 64;
  if (EMIT8) {
    unsigned char* ep = (unsigned char*)lds + wid * 3072;  // [32][96]
#pragma unroll
    for (int hf = 0; hf < 2; ++hf) {
#pragma unroll
      for (int fi = 0; fi < 2; ++fi) {
        const int fI = hf * 2 + fi;
        const int rl0 = fi * 16 + ((lane >> 4) << 2);
#pragma unroll
        for (int fj = 0; fj < 4; ++fj)
#pragma unroll
          for (int r = 0; r < 4; ++r)
            ep[(rl0 + r) * 96 + fj * 16 + lrow] = (unsigned char)f2fp8(acc[fI][fj][r]);
      }
#pragma unroll
      for (int i = 0; i < 2; ++i) {
        const int rl = (lane >> 2) + i * 16;
        const int cb = (lane & 3) * 16;
        uint4 val = *(const uint4*)&ep[rl * 96 + cb];
        const int grow = m0 + wr * 64 + hf * 32 + rl;
        if (grow < M)
          *(uint4*)(Y8 + (size_t)grow * 768 + colq + cb) = val;
      }
    }
  } else {
    ushort* ep = lds + wid * 2304;  // [32][72]
#pragma unroll
    for (int hf = 0; hf < 2; ++hf) {
#pragma unroll
      for (int fi = 0; fi < 2; ++fi) {
        const int fI = hf * 2 + fi;
        const int rl0 = fi * 16 + ((lane >> 4) << 2);
#pragma unroll
        for (int fj = 0; fj < 4; ++fj)
#pragma unroll
          for (int r = 0; r < 4; ++r)
            ep[(rl0 + r) * 72 + fj * 16 + lrow] = f2b(acc[fI][fj][r]);
      }
#pragma unroll
      for (int i = 0; i < 4; ++i) {
        const int rl = (lane >> 2) + (i & 1) * 16;
        const int oct = (lane & 3) + (i >> 1) * 4;
        v8s val = *(const v8s*)&ep[rl * 72 + oct * 8];
        const int grow = m0 + wr * 64 + hf * 32 + rl;
        if (grow < M)
          *(v8s*)(Y + (size_t)grow * 768 + colq + oct * 8) = val;
      }
    }
  }
}

// ------------------------------------------------------------------ agg + epilogue (bf16 tables)
template <int MODE, int WR>
__global__ __launch_bounds__(256) void aggepi_k(
    const ushort* __restrict__ Y, ushort* __restrict__ hout, ushort* __restrict__ raw,
    const int* __restrict__ off_in, const int* __restrict__ in_src,
    const int* __restrict__ off_out, const int* __restrict__ out_dst,
    const float* __restrict__ minA, const float* __restrict__ moutA,
    const float* __restrict__ bsum, const float* __restrict__ gma,
    const float* __restrict__ bta, const float* __restrict__ rmn, const float* __restrict__ rvr,
    int Mtot) {
  const int g = threadIdx.x >> 5;
  const int lane = threadIdx.x & 31;
  const int node = blockIdx.x * 8 + g;
  if (node >= Mtot) return;
  const int v = node;
  const int co = lane * 8;
  float acc[8] = {};
#pragma unroll
  for (int dir = 0; dir < 2; ++dir) {
    const int* offs = dir ? off_out : off_in;
    const int* nbr  = dir ? out_dst : in_src;
    const float* ma = dir ? moutA : minA;
    const ushort* Yg = Y + (dir ? 512 : 256) + co;
    const int s = offs[v], e = offs[v + 1];
    int i = s;
    for (; i + 4 <= e; i += 4) {
      int u[4]; float m[4];
#pragma unroll
      for (int t = 0; t < 4; ++t) {
        u[t] = nbr[i + t];
        m[t] = (MODE == 0) ? 1.f : ma[i + t];
      }
      v8s r[4];
#pragma unroll
      for (int t = 0; t < 4; ++t) r[t] = *(const v8s*)(Yg + (size_t)u[t] * 768);
#pragma unroll
      for (int t = 0; t < 4; ++t)
#pragma unroll
        for (int j = 0; j < 8; ++j) acc[j] += m[t] * b2f((ushort)r[t][j]);
    }
    for (; i < e; ++i) {
      int u = nbr[i];
      float m = (MODE == 0) ? 1.f : ma[i];
      v8s r = *(const v8s*)(Yg + (size_t)u * 768);
#pragma unroll
      for (int j = 0; j < 8; ++j) acc[j] += m * b2f((ushort)r[j]);
    }
  }
  if (WR) {
    v8s rw;
#pragma unroll
    for (int j = 0; j < 8; ++j) rw[j] = (short)f2b(acc[j]);
    *(v8s*)(raw + (size_t)v * 256 + co) = rw;
  }
  v8s ys = *(const v8s*)(Y + (size_t)v * 768 + co);
  v8s o;
#pragma unroll
  for (int j = 0; j < 8; ++j) {
    const int col = co + j;
    float val = acc[j] + b2f((ushort)ys[j]) + bsum[col];
    val = fmaxf(val, 0.f);
    val = (val - rmn[col]) * rsqrtf(rvr[col] + EPSc) * gma[col] + bta[col];
    o[j] = (short)f2b(val);
  }
  *(v8s*)(hout + (size_t)node * 256 + co) = o;
}

// ------------------------------------------------------------------ agg + epilogue (fp8 tables, dual-half batched)
__global__ __launch_bounds__(256) void aggepi8_k(
    const unsigned char* __restrict__ Y8, ushort* __restrict__ hout,
    const int* __restrict__ off_in, const int* __restrict__ in_src,
    const int* __restrict__ off_out, const int* __restrict__ out_dst,
    const float* __restrict__ minA, const float* __restrict__ moutA,
    const float* __restrict__ bsum, const float* __restrict__ gma,
    const float* __restrict__ bta, const float* __restrict__ rmn, const float* __restrict__ rvr) {
  const int g = threadIdx.x >> 5;
  const int lane = threadIdx.x & 31;
  const int node = blockIdx.x * 8 + g;
  if (node >= 2 * Nn) return;
  const int half = (node >= Nn) ? 1 : 0;
  const int v = node - half * Nn;
  const int co = lane * 8;
  float acc[8] = {};
#pragma unroll
  for (int dir = 0; dir < 2; ++dir) {
    const int* offs = dir ? off_out : off_in;
    const int* nbr  = dir ? out_dst : in_src;
    const float* ma = dir ? moutA : minA;
    const unsigned char* Yg = Y8 + (size_t)half * Nn * 768 + (dir ? 512 : 256) + co;
    const int s = offs[v], e = offs[v + 1];
    int i = s;
    for (; i + 4 <= e; i += 4) {
      int u[4]; float m[4];
#pragma unroll
      for (int t = 0; t < 4; ++t) {
        u[t] = nbr[i + t];
        float mv = ma[i + t];
        m[t] = half ? (1.f - mv) : mv;
      }
      uint2 r[4];
#pragma unroll
      for (int t = 0; t < 4; ++t) r[t] = *(const uint2*)(Yg + (size_t)u[t] * 768);
#pragma unroll
      for (int t = 0; t < 4; ++t) {
        float f[8];
        fp8x8_dec(r[t].x, r[t].y, f);
#pragma unroll
        for (int j = 0; j < 8; ++j) acc[j] += m[t] * f[j];
      }
    }
    for (; i < e; ++i) {
      int u = nbr[i];
      float mv = ma[i];
      float m = half ? (1.f - mv) : mv;
      uint2 r = *(const uint2*)(Yg + (size_t)u * 768);
      float f[8];
      fp8x8_dec(r.x, r.y, f);
#pragma unroll
      for (int j = 0; j < 8; ++j) acc[j] += m * f[j];
    }
  }
  uint2 rs = *(const uint2*)(Y8 + (size_t)(half * Nn + v) * 768 + co);
  float fs[8];
  fp8x8_dec(rs.x, rs.y, fs);
  v8s o;
#pragma unroll
  for (int j = 0; j < 8; ++j) {
    const int col = co + j;
    float val = acc[j] + fs[j] + bsum[col];
    val = fmaxf(val, 0.f);
    val = (val - rmn[col]) * rsqrtf(rvr[col] + EPSc) * gma[col] + bta[col];
    o[j] = (short)f2b(val);
  }
  *(v8s*)(hout + (size_t)node * 256 + co) = o;
}

// batched L0 comp half
__global__ void compl0_k(const ushort* __restrict__ Yx, const ushort* __restrict__ Aones,
                         const ushort* __restrict__ Asub, ushort* __restrict__ hout,
                         const float* __restrict__ bsum, const float* __restrict__ gma,
                         const float* __restrict__ bta, const float* __restrict__ rmn,
                         const float* __restrict__ rvr) {
  int i = blockIdx.x * 256 + threadIdx.x;
  if (i >= Nn * 32) return;
  const int v = i >> 5;
  const int co = (i & 31) * 8;
  v8s ys = *(const v8s*)(Yx + (size_t)v * 768 + co);
  v8s ao = *(const v8s*)(Aones + (size_t)v * 256 + co);
  v8s as = *(const v8s*)(Asub + (size_t)v * 256 + co);
  v8s o;
#pragma unroll
  for (int j = 0; j < 8; ++j) {
    const int col = co + j;
    float val = b2f((ushort)ys[j]) + b2f((ushort)ao[j]) - b2f((ushort)as[j]) + bsum[col];
    val = fmaxf(val, 0.f);
    val = (val - rmn[col]) * rsqrtf(rvr[col] + EPSc) * gma[col] + bta[col];
    o[j] = (short)f2b(val);
  }
  *(v8s*)(hout + (size_t)(Nn + v) * 256 + co) = o;
}

// ------------------------------------------------------------------ proj GEMM (mask MLP layer 1)
template <int EPI>
__global__ __launch_bounds__(256) void mfma_gemm2_k(
    const ushort* __restrict__ A, const ushort* __restrict__ W,
    ushort* __restrict__ Cout, int M, const float* __restrict__ bias) {
  __shared__ ushort eplds[4][32][72];
  const int tid = threadIdx.x;
  const int wid = tid >> 6, lane = tid & 63;
  const int wr = wid & 1, wc = wid >> 1;
  const int m0 = blockIdx.x * 64 + wr * 32;
  const int n0 = blockIdx.y * 128 + wc * 64;
  const int lrow = lane & 15;
  const int klo = (lane >> 4) * 8;
  int rowA[2];
#pragma unroll
  for (int fi = 0; fi < 2; ++fi) {
    int r = m0 + fi * 16 + lrow;
    rowA[fi] = (r < M) ? r : (M - 1);
  }
  v4f acc[2][4] = {};
#pragma unroll
  for (int c = 0; c < 8; ++c) {
    v8s a[2], b[4];
#pragma unroll
    for (int fi = 0; fi < 2; ++fi)
      a[fi] = *(const v8s*)(A + (size_t)rowA[fi] * 256 + c * 32 + klo);
#pragma unroll
    for (int fj = 0; fj < 4; ++fj)
      b[fj] = *(const v8s*)(W + (size_t)(n0 + fj * 16 + lrow) * 256 + c * 32 + klo);
#pragma unroll
    for (int fi = 0; fi < 2; ++fi)
#pragma unroll
      for (int fj = 0; fj < 4; ++fj)
        acc[fi][fj] = __builtin_amdgcn_mfma_f32_16x16x32_bf16(a[fi], b[fj], acc[fi][fj], 0, 0, 0);
  }
#pragma unroll
  for (int fj = 0; fj < 4; ++fj) {
    const int col = n0 + fj * 16 + lrow;
    const float bsv = bias ? bias[col] : 0.f;
#pragma unroll
    for (int fi = 0; fi < 2; ++fi) {
      const int rl0 = fi * 16 + ((lane >> 4) << 2);
#pragma unroll
      for (int r = 0; r < 4; ++r)
        eplds[wid][rl0 + r][fj * 16 + lrow] = f2b(acc[fi][fj][r] + bsv);
    }
  }
#pragma unroll
  for (int i = 0; i < 4; ++i) {
    const int rl = (lane >> 2) + (i & 1) * 16;
    const int oct = (lane & 3) + (i >> 1) * 4;
    v8s val = *(const v8s*)&eplds[wid][rl][oct * 8];
    const int grow = m0 + rl;
    if (grow < M)
      *(v8s*)(Cout + (size_t)grow * 256 + n0 + oct * 8) = val;
  }
}

// ------------------------------------------------------------------ edge MLP over out-CSR order
__global__ __launch_bounds__(256) void edge_mlp4_k(const ushort* __restrict__ P,
                                                   const int* __restrict__ out_srcn,
                                                   const int* __restrict__ out_dst,
                                                   const int* __restrict__ out_eid,
                                                   const ushort* __restrict__ W2b,
                                                   const float* __restrict__ b2, const float* __restrict__ w3,
                                                   const float* __restrict__ b3,
                                                   float* __restrict__ maskOut, float* __restrict__ moutA) {
  const int tid = threadIdx.x;
  const int w = tid >> 6, lane = tid & 63;
  const int e0 = blockIdx.x * 64 + w * 16;
  const int le = lane & 15;
  const int kq = lane >> 4;
  const int klo = kq * 8;
  const int pA = e0 + le;
  const int s_ = out_srcn[pA], d_ = out_dst[pA];
  const ushort* ps = P + (size_t)s_ * 256;
  const ushort* pd = P + (size_t)d_ * 256 + 128;
  v8s as[4], ad[4];
#pragma unroll
  for (int c = 0; c < 4; ++c) {
    as[c] = *(const v8s*)(ps + c * 32 + klo);
    ad[c] = *(const v8s*)(pd + c * 32 + klo);
  }
  v4f acc[4] = {};
#pragma unroll
  for (int c = 0; c < 4; ++c) {
    v8s h;
#pragma unroll
    for (int j = 0; j < 8; ++j) {
      float v = fmaxf(b2f((ushort)as[c][j]) + b2f((ushort)ad[c][j]), 0.f);
      h[j] = (short)f2b(v);
    }
#pragma unroll
    for (int fj = 0; fj < 4; ++fj) {
      v8s b = *(const v8s*)(W2b + (size_t)(fj * 16 + le) * 128 + c * 32 + klo);
      acc[fj] = __builtin_amdgcn_mfma_f32_16x16x32_bf16(h, b, acc[fj], 0, 0, 0);
    }
  }
  float b2v[4], w3v[4];
#pragma unroll
  for (int fj = 0; fj < 4; ++fj) { b2v[fj] = b2[fj * 16 + le]; w3v[fj] = w3[fj * 16 + le]; }
  const float b3v = b3[0];
#pragma unroll
  for (int r = 0; r < 4; ++r) {
    float val = 0.f;
#pragma unroll
    for (int fj = 0; fj < 4; ++fj)
      val += fmaxf(acc[fj][r] + b2v[fj], 0.f) * w3v[fj];
    val += __shfl_xor(val, 1);
    val += __shfl_xor(val, 2);
    val += __shfl_xor(val, 4);
    val += __shfl_xor(val, 8);
    if (le == 0) {
      int pos = e0 + kq * 4 + r;
      float sig = 1.0f / (1.0f + expf(-(val + b3v)));
      moutA[pos] = sig;
      maskOut[out_eid[pos]] = sig;
    }
  }
}

// ------------------------------------------------------------------ pooling / tails
__global__ __launch_bounds__(256) void gemb_sum_k(const ushort* __restrict__ h, const int* __restrict__ batch,
                                                  float* __restrict__ gsum, int batched) {
  const int halfBlocks = Nn / 16;
  int blk = blockIdx.x;
  int half = 0, bi = blk;
  if (batched) { half = (blk >= halfBlocks) ? 1 : 0; bi = blk - half * halfBlocks; }
  const int v0 = bi * 16;
  const int tid = threadIdx.x;
  const size_t base = (size_t)half * Nn;
  float* out = gsum + (size_t)half * (Bb * Dd);
  float acc = 0.0f;
  int curb = batch[v0];
  for (int i = 0; i < 16; ++i) {
    int v = v0 + i;
    int b = batch[v];
    if (b != curb) { atomicAdd(&out[curb * Dd + tid], acc); acc = 0.0f; curb = b; }
    acc += b2f(h[(base + v) * Dd + tid]);
  }
  atomicAdd(&out[curb * Dd + tid], acc);
}

__global__ void gemb_scale_k(float* __restrict__ g, const float* __restrict__ cntf) {
  int blk = blockIdx.x;
  int b = blk & 15;
  g[blk * Dd + threadIdx.x] /= fmaxf(cntf[b], 1.0f);
}

__global__ void anchor_k(const float* __restrict__ g, const float* __restrict__ anchors,
                         float* __restrict__ s_out) {
  __shared__ float red4[4];
  const int b = blockIdx.x, tid = threadIdx.x;
  float gv = g[b * Dd + tid];
  float total = 0.0f;
  for (int k = 0; k < 6; ++k) {
    float d = gv - anchors[k * Dd + tid];
    float v = d * d;
    for (int o = 32; o > 0; o >>= 1) v += __shfl_xor(v, o);
    if ((tid & 63) == 0) red4[tid >> 6] = v;
    __syncthreads();
    if (tid == 0) total += sqrtf(red4[0] + red4[1] + red4[2] + red4[3]);
    __syncthreads();
  }
  if (tid == 0) s_out[b] = total;
}

__global__ void logits_k(const float* __restrict__ gsub, const float* __restrict__ gcomp,
                         const float* __restrict__ Wc, const float* __restrict__ bc,
                         float* __restrict__ outL) {
  __shared__ float red4[4];
  const int blk = blockIdx.x;
  const int set = blk >> 4, b = blk & 15;
  const float* g = set ? gcomp : gsub;
  const int tid = threadIdx.x;
  float gv = g[b * Dd + tid];
  for (int c = 0; c < 2; ++c) {
    float v = gv * Wc[c * Dd + tid];
    for (int o = 32; o > 0; o >>= 1) v += __shfl_xor(v, o);
    if ((tid & 63) == 0) red4[tid >> 6] = v;
    __syncthreads();
    if (tid == 0) outL[set * 32 + b * 2 + c] = red4[0] + red4[1] + red4[2] + red4[3] + bc[c];
    __syncthreads();
  }
}

__global__ void final_k(const float* __restrict__ L, const int* __restrict__ labels,
                        const float* __restrict__ s_orig, const float* __restrict__ s_sub,
                        float* __restrict__ out) {
  if (threadIdx.x == 0) {
    float Lp = 0, Lu = 0, La = 0;
    const float u = 0.5f;
    for (int b = 0; b < 16; ++b) {
      float l0 = L[b * 2], l1 = L[b * 2 + 1];
      float m = fmaxf(l0, l1);
      float lse = m + logf(expf(l0 - m) + expf(l1 - m));
      int lab = labels[b];
      Lp += -((lab ? l1 : l0) - lse);
      float c0 = L[32 + b * 2], c1 = L[32 + b * 2 + 1];
      float mm = fmaxf(c0, c1);
      float e0 = expf(c0 - mm), e1 = expf(c1 - mm), Z = e0 + e1;
      Lu += u * (logf(u) - logf(e0 / Z + 1e-8f)) + u * (logf(u) - logf(e1 / Z + 1e-8f));
      float dd = s_sub[b] - s_orig[b];
      La += dd * dd;
    }
    Lp /= 16.0f; Lu /= 16.0f; La /= 16.0f;
    out[0] = 0.5f * Lp + 0.3f * Lu + 0.2f * La;
    out[1] = Lp; out[2] = Lu; out[3] = La;
  }
}

// ------------------------------------------------------------------ host
extern "C" void kernel_launch(void* const* d_in, const int* in_sizes, int n_in,
                              void* d_out, int out_size, void* d_ws, size_t ws_size,
                              hipStream_t stream) {
  (void)in_sizes; (void)n_in; (void)out_size; (void)ws_size;
  const float* x    = (const float*)d_in[0];
  const int* ei     = (const int*)d_in[1];
  const int* batch  = (const int*)d_in[2];
  const int* labels = (const int*)d_in[3];
  const float* mw1 = (const float*)d_in[4];
  const float* mb1 = (const float*)d_in[5];
  const float* mw2 = (const float*)d_in[6];
  const float* mb2 = (const float*)d_in[7];
  const float* mw3 = (const float*)d_in[8];
  const float* mb3 = (const float*)d_in[9];
  const float* Ws   = (const float*)d_in[10];
  const float* bs   = (const float*)d_in[11];
  const float* Win  = (const float*)d_in[12];
  const float* bin_ = (const float*)d_in[13];
  const float* Wout = (const float*)d_in[14];
  const float* bout = (const float*)d_in[15];
  const float* gma  = (const float*)d_in[16];
  const float* bta  = (const float*)d_in[17];
  const float* rmn  = (const float*)d_in[18];
  const float* rvr  = (const float*)d_in[19];
  const float* anchors = (const float*)d_in[20];
  const float* Wc   = (const float*)d_in[21];
  const float* bc   = (const float*)d_in[22];
  const int* srcp = ei;
  const int* dstp = ei + Ee;

  const size_t NH = (size_t)Nn * Dd;
  const size_t NY = (size_t)Nn * 768;
  ushort* xb   = (ushort*)d_ws;
  ushort* hA   = xb + NH;
  ushort* hB   = hA + 2 * NH;
  ushort* Yx   = hB + 2 * NH;
  ushort* Ybuf = Yx + NY;
  ushort* Pb   = Ybuf;
  unsigned char* Y8 = (unsigned char*)Ybuf;
  ushort* Aones = Ybuf + 2 * NY;
  ushort* Asub  = Aones + NH;
  ushort* Wsb   = Asub + NH;
  ushort* Winb  = Wsb + 3 * 65536;
  ushort* Woutb = Winb + 3 * 65536;
  ushort* Wcombb = Woutb + 3 * 65536;
  ushort* W2b    = Wcombb + 65536;
  float* bcomb = (float*)(W2b + 8192);
  float* minA  = bcomb + 256;
  float* moutA = minA + Ee;
  int* off_in   = (int*)(moutA + Ee);
  int* off_out  = off_in + (Nn + 1);
  int* cur_in   = off_out + (Nn + 1);
  int* cur_out  = cur_in + Nn;
  int* in_src   = cur_out + Nn;
  int* in_eid   = in_src + Ee;
  int* out_dst  = in_eid + Ee;
  int* out_eid  = out_dst + Ee;
  int* out_srcn = out_eid + Ee;
  int* counts_in  = out_srcn + Ee;
  int* counts_out = counts_in + Nn;
  float* cntf      = (float*)(counts_out + Nn);
  float* gemb_orig = cntf + Bb;
  float* gemb_sub  = gemb_orig + Bb * Dd;
  float* gemb_comp = gemb_sub + Bb * Dd;
  float* bsum    = gemb_comp + Bb * Dd;
  float* s_orig  = bsum + 3 * Dd;
  float* s_sub   = s_orig + Bb;
  float* logitsb = s_sub + Bb;

  float* outF = (float*)d_out;
  float* maskp = outF + 4;

  const size_t zero_bytes = (char*)bsum - (char*)counts_in;
  hipMemsetAsync(counts_in, 0, zero_bytes, stream);

  hist_edges_k<<<(Ee + 255) / 256, 256, 0, stream>>>(srcp, dstp, counts_in, counts_out);
  cnt_batch_k<<<1, 64, 0, stream>>>(batch, cntf);
  scan_k<<<1, 1024, 0, stream>>>(counts_in, counts_out, off_in, off_out, cur_in, cur_out);
  scatter_k<<<(Ee + 255) / 256, 256, 0, stream>>>(srcp, dstp, cur_in, cur_out, in_src, in_eid,
                                                  out_dst, out_eid, out_srcn);
  prep_bsum_k<<<1, 256, 0, stream>>>(bs, bin_, bout, bsum);

  c_f2b_k<<<(3 * 65536 + 255) / 256, 256, 0, stream>>>(Ws, Wsb, 3 * 65536);
  c_f2b_k<<<(3 * 65536 + 255) / 256, 256, 0, stream>>>(Win, Winb, 3 * 65536);
  c_f2b_k<<<(3 * 65536 + 255) / 256, 256, 0, stream>>>(Wout, Woutb, 3 * 65536);
  prep_mlp_k<<<256, 256, 0, stream>>>(mw1, mb1, mw2, Wcombb, W2b, bcomb);

  auto run_gemm768 = [&](const ushort* h, ushort* Yout, int M, int l) {
    dim3 gg((M + 127) / 128, 6);
    gemm768t_k<0><<<gg, 256, 0, stream>>>(h, Wsb + (size_t)l * 65536, Winb + (size_t)l * 65536,
                                          Woutb + (size_t)l * 65536, Yout, nullptr, M);
  };
  auto run_gemm768_8 = [&](const ushort* h, int M, int l) {
    dim3 gg((M + 127) / 128, 6);
    gemm768t_k<1><<<gg, 256, 0, stream>>>(h, Wsb + (size_t)l * 65536, Winb + (size_t)l * 65536,
                                          Woutb + (size_t)l * 65536, nullptr, Y8, M);
  };
  auto bn = [&](int l) { return bsum + l * 256; };
  const int aggN = (Nn + 7) / 8;
  const int agg2N = (2 * Nn + 7) / 8;

  // ---- encoder #1 (ones mask), bf16 throughout
  copyxb_k<<<(Nn * Dd / 4 + 255) / 256, 256, 0, stream>>>(x, xb);
  run_gemm768(xb, Yx, Nn, 0);
  aggepi_k<0, 1><<<aggN, 256, 0, stream>>>(
      Yx, hB, Aones, off_in, in_src, off_out, out_dst, nullptr, nullptr,
      bn(0), gma, bta, rmn, rvr, Nn);
  run_gemm768(hB, Ybuf, Nn, 1);
  aggepi_k<0, 0><<<aggN, 256, 0, stream>>>(
      Ybuf, hA, nullptr, off_in, in_src, off_out, out_dst, nullptr, nullptr,
      bn(1), gma + 256, bta + 256, rmn + 256, rvr + 256, Nn);
  run_gemm768(hA, Ybuf, Nn, 2);
  aggepi_k<0, 0><<<aggN, 256, 0, stream>>>(
      Ybuf, hB, nullptr, off_in, in_src, off_out, out_dst, nullptr, nullptr,
      bn(2), gma + 512, bta + 512, rmn + 512, rvr + 512, Nn);
  // node_emb = hB

  gemb_sum_k<<<Nn / 16, 256, 0, stream>>>(hB, batch, gemb_orig, 0);
  gemb_scale_k<<<Bb, 256, 0, stream>>>(gemb_orig, cntf);
  anchor_k<<<Bb, 256, 0, stream>>>(gemb_orig, anchors, s_orig);

  // ---- packed projection P (Pb aliases Ybuf)
  {
    dim3 gp((Nn + 63) / 64, 2);
    mfma_gemm2_k<3><<<gp, 256, 0, stream>>>(hB, Wcombb, Pb, Nn, bcomb);
  }
  edge_mlp4_k<<<Ee / 64, 256, 0, stream>>>(Pb, out_srcn, out_dst, out_eid,
                                           W2b, mb2, mw3, mb3, maskp, moutA);
  permmask_k<<<(Ee + 255) / 256, 256, 0, stream>>>(maskp, in_eid, minA);

  // ---- batched encoders #2/#3 (mask & 1-mask)
  aggepi_k<1, 1><<<aggN, 256, 0, stream>>>(
      Yx, hA, Asub, off_in, in_src, off_out, out_dst, minA, moutA,
      bn(0), gma, bta, rmn, rvr, Nn);
  compl0_k<<<(Nn * 32 + 255) / 256, 256, 0, stream>>>(Yx, Aones, Asub, hA,
                                                      bn(0), gma, bta, rmn, rvr);
  // L1 (fp8 Y table + dual-half fp8 agg)
  run_gemm768_8(hA, 2 * Nn, 1);
  aggepi8_k<<<agg2N, 256, 0, stream>>>(
      Y8, hB, off_in, in_src, off_out, out_dst, minA, moutA,
      bn(1), gma + 256, bta + 256, rmn + 256, rvr + 256);
  // L2
  run_gemm768_8(hB, 2 * Nn, 2);
  aggepi8_k<<<agg2N, 256, 0, stream>>>(
      Y8, hA, off_in, in_src, off_out, out_dst, minA, moutA,
      bn(2), gma + 512, bta + 512, rmn + 512, rvr + 512);
  // hA = [h_sub; h_comp]

  gemb_sum_k<<<2 * (Nn / 16), 256, 0, stream>>>(hA, batch, gemb_sub, 1);
  gemb_scale_k<<<2 * Bb, 256, 0, stream>>>(gemb_sub, cntf);
  anchor_k<<<Bb, 256, 0, stream>>>(gemb_sub, anchors, s_sub);
  logits_k<<<2 * Bb, 256, 0, stream>>>(gemb_sub, gemb_comp, Wc, bc, logitsb);
  final_k<<<1, 64, 0, stream>>>(logitsb, labels, s_orig, s_sub, outF);
}